// Round 11
// baseline (13.677 us; speedup 1.0000x reference)
//
#include <hip/hip_runtime.h>
#include <math.h>

// Numerics FROZEN (passed rounds 6/7/9/10): jax XLA:CPU f32 model —
//   f32 linspace t=RN(i*RN(1/31)); correctly-rounded powers (f64-emulated);
//   samples dot = sequential mul-then-add (no fma); cross: c0=RN(y*sy),
//   c=RN(fma(x,sx,c0)); e=RN(p2-2c) (2c exact -> fma(-2,c,p2) identical);
//   d2=RN(e+s2); min (exact, order-free); clamp; sqrt; r=fma(md,.25,1e-6);
//   w=2^(0.35*log2 r) via HW transcendentals (error << threshold margin).
// Round 11 (pure perf): sample-PAIRED loop with v_min3_f32 (2 mins -> 1 issue,
// min is exact) + 16 px/thread (readlane/c0 amortized over 2x pixels).
#define OPAQ(x) asm volatile("" : "+v"(x))
typedef float f2 __attribute__((ext_vector_type(2)));

#define HH 256
#define WW 256
#define NS 32
#define NB 32

__device__ __forceinline__ uint64_t rlane_dup(float v, int lane) {
    unsigned u = (unsigned)__builtin_amdgcn_readlane(__builtin_bit_cast(int, v), lane);
    return ((uint64_t)u << 32) | (uint64_t)u;   // SALU pack: same f32 both halves
}
__device__ __forceinline__ f2 pk_mul_vs(f2 a, uint64_t b) {
    f2 d; asm("v_pk_mul_f32 %0, %1, %2" : "=v"(d) : "v"(a), "s"(b)); return d;
}
__device__ __forceinline__ f2 pk_fma_vsv(f2 a, uint64_t b, f2 c) {
    f2 d; asm("v_pk_fma_f32 %0, %1, %2, %3" : "=v"(d) : "v"(a), "s"(b), "v"(c)); return d;
}
__device__ __forceinline__ f2 pk_fma_vvv(f2 a, f2 b, f2 c) {
    f2 d; asm("v_pk_fma_f32 %0, %1, %2, %3" : "=v"(d) : "v"(a), "v"(b), "v"(c)); return d;
}
__device__ __forceinline__ f2 pk_add_vs(f2 a, uint64_t b) {
    f2 d; asm("v_pk_add_f32 %0, %1, %2" : "=v"(d) : "v"(a), "s"(b)); return d;
}
__device__ __forceinline__ float min3f(float a, float b, float c) {
    float r; asm("v_min3_f32 %0, %1, %2, %3" : "=v"(r) : "v"(a), "v"(b), "v"(c)); return r;
}
__device__ __forceinline__ float hw_sqrt(float x) {
    float r; asm("v_sqrt_f32 %0, %1" : "=v"(r) : "v"(x)); return r;
}
__device__ __forceinline__ float hw_log2(float x) {
    float r; asm("v_log_f32 %0, %1" : "=v"(r) : "v"(x)); return r;
}
__device__ __forceinline__ float hw_exp2(float x) {
    float r; asm("v_exp_f32 %0, %1" : "=v"(r) : "v"(x)); return r;
}

// ---- frozen numeric core: sample s of one curve (EXACT round-6 ops) ----
__device__ __forceinline__ void curve_sample(const float* kp, int s,
                                             float& accy_o, float& accx_o, float& s2_o) {
    const float STEP = 1.0f / 31.0f;       // RN(1/31)
    float t = (float)s * STEP; OPAQ(t);    // f32 linspace (i=31 -> 1.0 after RN)
    float u = 1.0f - t;        OPAQ(u);
    // correctly-rounded powers (glibc powf) emulated via exact f64 products
    float t2 = (float)((double)t * (double)t);
    float t3 = (float)((double)t * (double)t * (double)t);
    float u2 = (float)((double)u * (double)u);
    float u3 = (float)((double)u * (double)u * (double)u);
    float b0 = u3;
    float m1 = 3.0f * t;  OPAQ(m1); float b1 = m1 * u2; OPAQ(b1);
    float m2 = 3.0f * t2; OPAQ(m2); float b2 = m2 * u;  OPAQ(b2);
    float b3 = t3;

    float ky0 = kp[0] * 256.0f, kx0 = kp[1] * 256.0f;   // exact (x 2^8)
    float ky1 = kp[2] * 256.0f, kx1 = kp[3] * 256.0f;
    float ky2 = kp[4] * 256.0f, kx2 = kp[5] * 256.0f;
    float ky3 = kp[6] * 256.0f, kx3 = kp[7] * 256.0f;

    // samples dot: sequential mul THEN add, no fma (XLA naive small-dot)
    float p, accy, accx;
    p = b0 * ky0; OPAQ(p); accy = p;
    p = b1 * ky1; OPAQ(p); accy = accy + p; OPAQ(accy);
    p = b2 * ky2; OPAQ(p); accy = accy + p; OPAQ(accy);
    p = b3 * ky3; OPAQ(p); accy = accy + p; OPAQ(accy);

    p = b0 * kx0; OPAQ(p); accx = p;
    p = b1 * kx1; OPAQ(p); accx = accx + p; OPAQ(accx);
    p = b2 * kx2; OPAQ(p); accx = accx + p; OPAQ(accx);
    p = b3 * kx3; OPAQ(p); accx = accx + p; OPAQ(accx);

    float q1 = accy * accy; OPAQ(q1);
    float q2 = accx * accx; OPAQ(q2);
    accy_o = accy; accx_o = accx; s2_o = q1 + q2;
}

__global__ __launch_bounds__(256) void curve_render_kernel(
    const float* __restrict__ in, float* __restrict__ out)
{
    const int b    = blockIdx.x >> 4;          // image
    const int rg   = blockIdx.x & 15;          // 16-row group
    const int wid  = threadIdx.x >> 6;         // wave: 4 rows
    const int lane = threadIdx.x & 63;
    const int row  = (rg << 4) + (wid << 2) + (lane >> 4);
    const int xb   = (lane & 15) << 4;         // 16 px per thread along x

    // every lane computes sample (lane & 31); lanes 32-63 duplicate 0-31
    float v_sy, v_sx, v_s2;
    curve_sample(in + b * 8, lane & 31, v_sy, v_sx, v_s2);

    const float y = (float)row;
    const f2 yp = {y, y};
    const f2 M2 = {-2.0f, -2.0f};
    const float yy = y * y;                    // exact

    f2 xp[8], q[8];
    #pragma unroll
    for (int i = 0; i < 8; ++i) {
        float xa = (float)(xb + 2 * i), xc = (float)(xb + 2 * i + 1);
        xp[i] = (f2){xa, xc};
        q[i]  = (f2){yy + xa * xa, yy + xc * xc};   // p2, exact ints < 2^24
    }

    const float INF = 3.4028234663852886e38f;
    float mm[16];
    #pragma unroll
    for (int i = 0; i < 16; ++i) mm[i] = INF;

    #pragma unroll
    for (int s = 0; s < NS; s += 2) {
        const uint64_t syA = rlane_dup(v_sy, s), syB = rlane_dup(v_sy, s + 1);
        const uint64_t sxA = rlane_dup(v_sx, s), sxB = rlane_dup(v_sx, s + 1);
        const uint64_t sA2 = rlane_dup(v_s2, s), sB2 = rlane_dup(v_s2, s + 1);
        // c0 = RN(y*sy) per sample, duplicated in both halves
        const f2 c0A = pk_mul_vs(yp, syA);
        const f2 c0B = pk_mul_vs(yp, syB);
        #pragma unroll
        for (int i = 0; i < 8; ++i) {
            // per pixel-pair, per sample: c = fma(x,sx,c0); e = RN(p2-2c)
            // (2c exact -> fma(c,-2,p2) == RN(p2-2c)); d2 = RN(e+s2)
            f2 cA = pk_fma_vsv(xp[i], sxA, c0A);
            f2 eA = pk_fma_vvv(cA, M2, q[i]);
            f2 dA = pk_add_vs(eA, sA2);
            f2 cB = pk_fma_vsv(xp[i], sxB, c0B);
            f2 eB = pk_fma_vvv(cB, M2, q[i]);
            f2 dB = pk_add_vs(eB, sB2);
            // two sample-mins fused: exact, order-free
            mm[2 * i]     = min3f(mm[2 * i],     dA.x, dB.x);
            mm[2 * i + 1] = min3f(mm[2 * i + 1], dA.y, dB.y);
        }
    }

    // tail: clamp, HW sqrt, r = fma(md,0.25,1e-6), w = 2^(0.35*log2 r)
    float o[16];
    #pragma unroll
    for (int i = 0; i < 16; ++i) {
        float md = hw_sqrt(fmaxf(mm[i], 0.0f));
        float r  = fmaf(md, 0.25f, 1e-6f);
        o[i] = 1.0f - hw_exp2(0.35f * hw_log2(r));
    }

    const int idx = (b * HH + row) * WW + xb;
    #pragma unroll
    for (int i = 0; i < 4; ++i) {
        *reinterpret_cast<float4*>(out + idx + 4 * i) =
            make_float4(o[4 * i], o[4 * i + 1], o[4 * i + 2], o[4 * i + 3]);
    }
}

extern "C" void kernel_launch(void* const* d_in, const int* in_sizes, int n_in,
                              void* d_out, int out_size, void* d_ws, size_t ws_size,
                              hipStream_t stream) {
    const float* in = (const float*)d_in[0];
    float* out = (float*)d_out;
    // 32 images x 16 groups of 16 rows; 256 threads = 4 waves, 16 px/thread
    curve_render_kernel<<<dim3(NB * 16), dim3(256), 0, stream>>>(in, out);
}

// Round 12
// 13.105 us; speedup vs baseline: 1.0436x; 1.0436x over previous
//
#include <hip/hip_runtime.h>
#include <math.h>

// Numerics FROZEN (passed rounds 6/7/9/10): jax XLA:CPU f32 model —
//   f32 linspace t=RN(i*RN(1/31)); correctly-rounded powers (f64-emulated);
//   samples dot = sequential mul-then-add (no fma); cross: c0=RN(y*sy),
//   c=RN(fma(x,sx,c0)); e=RN(p2-2c) (2c exact -> fma(-2,c,p2) identical);
//   d2=RN(e+s2); min (exact, order-free); clamp; sqrt; r=fma(md,.25,1e-6);
//   w=2^(0.35*log2 r) via HW transcendentals (error << threshold margin).
// FINAL (round 12 = round 10 verbatim, best measured 13.16 us):
//   packed FP32 (VOP3P v_pk_*, 2 f32/instr, bit-identical IEEE per half),
//   8 px/thread, per-sample scalars broadcast to SGPR pairs via SALU.
//   R11's min3+16px variant regressed (13.68) -> reverted.
#define OPAQ(x) asm volatile("" : "+v"(x))
typedef float f2 __attribute__((ext_vector_type(2)));

#define HH 256
#define WW 256
#define NS 32
#define NB 32

__device__ __forceinline__ uint64_t rlane_dup(float v, int lane) {
    unsigned u = (unsigned)__builtin_amdgcn_readlane(__builtin_bit_cast(int, v), lane);
    return ((uint64_t)u << 32) | (uint64_t)u;   // SALU pack: same f32 in both halves
}
__device__ __forceinline__ f2 pk_mul_vs(f2 a, uint64_t b) {
    f2 d; asm("v_pk_mul_f32 %0, %1, %2" : "=v"(d) : "v"(a), "s"(b)); return d;
}
__device__ __forceinline__ f2 pk_fma_vsv(f2 a, uint64_t b, f2 c) {
    f2 d; asm("v_pk_fma_f32 %0, %1, %2, %3" : "=v"(d) : "v"(a), "s"(b), "v"(c)); return d;
}
__device__ __forceinline__ f2 pk_fma_vvv(f2 a, f2 b, f2 c) {
    f2 d; asm("v_pk_fma_f32 %0, %1, %2, %3" : "=v"(d) : "v"(a), "v"(b), "v"(c)); return d;
}
__device__ __forceinline__ f2 pk_add_vs(f2 a, uint64_t b) {
    f2 d; asm("v_pk_add_f32 %0, %1, %2" : "=v"(d) : "v"(a), "s"(b)); return d;
}
__device__ __forceinline__ float hw_sqrt(float x) {
    float r; asm("v_sqrt_f32 %0, %1" : "=v"(r) : "v"(x)); return r;
}
__device__ __forceinline__ float hw_log2(float x) {
    float r; asm("v_log_f32 %0, %1" : "=v"(r) : "v"(x)); return r;
}
__device__ __forceinline__ float hw_exp2(float x) {
    float r; asm("v_exp_f32 %0, %1" : "=v"(r) : "v"(x)); return r;
}

// ---- frozen numeric core: sample s of one curve (EXACT round-6 ops) ----
__device__ __forceinline__ void curve_sample(const float* kp, int s,
                                             float& accy_o, float& accx_o, float& s2_o) {
    const float STEP = 1.0f / 31.0f;       // RN(1/31)
    float t = (float)s * STEP; OPAQ(t);    // f32 linspace (i=31 -> 1.0 after RN)
    float u = 1.0f - t;        OPAQ(u);
    // correctly-rounded powers (glibc powf) emulated via exact f64 products
    float t2 = (float)((double)t * (double)t);
    float t3 = (float)((double)t * (double)t * (double)t);
    float u2 = (float)((double)u * (double)u);
    float u3 = (float)((double)u * (double)u * (double)u);
    float b0 = u3;
    float m1 = 3.0f * t;  OPAQ(m1); float b1 = m1 * u2; OPAQ(b1);
    float m2 = 3.0f * t2; OPAQ(m2); float b2 = m2 * u;  OPAQ(b2);
    float b3 = t3;

    float ky0 = kp[0] * 256.0f, kx0 = kp[1] * 256.0f;   // exact (x 2^8)
    float ky1 = kp[2] * 256.0f, kx1 = kp[3] * 256.0f;
    float ky2 = kp[4] * 256.0f, kx2 = kp[5] * 256.0f;
    float ky3 = kp[6] * 256.0f, kx3 = kp[7] * 256.0f;

    // samples dot: sequential mul THEN add, no fma (XLA naive small-dot)
    float p, accy, accx;
    p = b0 * ky0; OPAQ(p); accy = p;
    p = b1 * ky1; OPAQ(p); accy = accy + p; OPAQ(accy);
    p = b2 * ky2; OPAQ(p); accy = accy + p; OPAQ(accy);
    p = b3 * ky3; OPAQ(p); accy = accy + p; OPAQ(accy);

    p = b0 * kx0; OPAQ(p); accx = p;
    p = b1 * kx1; OPAQ(p); accx = accx + p; OPAQ(accx);
    p = b2 * kx2; OPAQ(p); accx = accx + p; OPAQ(accx);
    p = b3 * kx3; OPAQ(p); accx = accx + p; OPAQ(accx);

    float q1 = accy * accy; OPAQ(q1);
    float q2 = accx * accx; OPAQ(q2);
    accy_o = accy; accx_o = accx; s2_o = q1 + q2;
}

__global__ __launch_bounds__(256) void curve_render_kernel(
    const float* __restrict__ in, float* __restrict__ out)
{
    const int b    = blockIdx.x >> 5;          // image
    const int rg   = blockIdx.x & 31;          // 8-row group
    const int wid  = threadIdx.x >> 6;         // wave: 2 rows
    const int lane = threadIdx.x & 63;
    const int row  = (rg << 3) + (wid << 1) + (lane >> 5);
    const int xb   = (lane & 31) << 3;         // 8 px per thread along x

    // every lane computes sample (lane & 31); lanes 32-63 duplicate 0-31
    float v_sy, v_sx, v_s2;
    curve_sample(in + b * 8, lane & 31, v_sy, v_sx, v_s2);

    const float y = (float)row;
    f2 yp = {y, y};
    const f2 M2 = {-2.0f, -2.0f};

    f2 xp0 = {(float)xb,       (float)(xb + 1)};
    f2 xp1 = {(float)(xb + 2), (float)(xb + 3)};
    f2 xp2 = {(float)(xb + 4), (float)(xb + 5)};
    f2 xp3 = {(float)(xb + 6), (float)(xb + 7)};
    const float yy = y * y;                    // exact
    f2 q0 = {yy + xp0.x * xp0.x, yy + xp0.y * xp0.y};   // p2, exact ints
    f2 q1 = {yy + xp1.x * xp1.x, yy + xp1.y * xp1.y};
    f2 q2 = {yy + xp2.x * xp2.x, yy + xp2.y * xp2.y};
    f2 q3 = {yy + xp3.x * xp3.x, yy + xp3.y * xp3.y};

    const float INF = 3.4028234663852886e38f;
    float m0 = INF, m1 = INF, m2 = INF, m3 = INF;
    float m4 = INF, m5 = INF, m6 = INF, m7 = INF;

    #pragma unroll
    for (int s = 0; s < NS; ++s) {
        const uint64_t syy = rlane_dup(v_sy, s);   // SGPR pair (SALU pack)
        const uint64_t sxx = rlane_dup(v_sx, s);
        const uint64_t s22 = rlane_dup(v_s2, s);
        // c0 = RN(y*sy), duplicated in both halves via (y,y)
        f2 c0 = pk_mul_vs(yp, syy);
        f2 c, e, d;
        c = pk_fma_vsv(xp0, sxx, c0); e = pk_fma_vvv(c, M2, q0); d = pk_add_vs(e, s22);
        m0 = fminf(m0, d.x); m1 = fminf(m1, d.y);
        c = pk_fma_vsv(xp1, sxx, c0); e = pk_fma_vvv(c, M2, q1); d = pk_add_vs(e, s22);
        m2 = fminf(m2, d.x); m3 = fminf(m3, d.y);
        c = pk_fma_vsv(xp2, sxx, c0); e = pk_fma_vvv(c, M2, q2); d = pk_add_vs(e, s22);
        m4 = fminf(m4, d.x); m5 = fminf(m5, d.y);
        c = pk_fma_vsv(xp3, sxx, c0); e = pk_fma_vvv(c, M2, q3); d = pk_add_vs(e, s22);
        m6 = fminf(m6, d.x); m7 = fminf(m7, d.y);
    }

    // tail: clamp, HW sqrt, r = fma(md,0.25,1e-6), w = 2^(0.35*log2 r)
    float o0, o1, o2, o3, o4, o5, o6, o7;
    #define TAIL(mi, oi) { \
        float md = hw_sqrt(fmaxf(mi, 0.0f)); \
        float r  = fmaf(md, 0.25f, 1e-6f); \
        oi = 1.0f - hw_exp2(0.35f * hw_log2(r)); }
    TAIL(m0, o0) TAIL(m1, o1) TAIL(m2, o2) TAIL(m3, o3)
    TAIL(m4, o4) TAIL(m5, o5) TAIL(m6, o6) TAIL(m7, o7)
    #undef TAIL

    const int idx = (b * HH + row) * WW + xb;
    *reinterpret_cast<float4*>(out + idx)     = make_float4(o0, o1, o2, o3);
    *reinterpret_cast<float4*>(out + idx + 4) = make_float4(o4, o5, o6, o7);
}

extern "C" void kernel_launch(void* const* d_in, const int* in_sizes, int n_in,
                              void* d_out, int out_size, void* d_ws, size_t ws_size,
                              hipStream_t stream) {
    const float* in = (const float*)d_in[0];
    float* out = (float*)d_out;
    // 32 images x 32 groups of 8 rows; 256 threads = 4 waves = 8 rows, 8 px/thread
    curve_render_kernel<<<dim3(NB * 32), dim3(256), 0, stream>>>(in, out);
}